// Round 1
// baseline (258.232 us; speedup 1.0000x reference)
//
#include <hip/hip_runtime.h>

// MGN_NET: 3x NNConv(mean) + ReLU, then pairwise-L1 CBT [35x35].
// All fp32. ws layout (floats):
//   x1[35*256]@0, x2[35*256]@8960, x3[35*64]@17920,
//   agg1[8960]@20160, agg2[8960]@29120, agg3[2240]@38080, cnt[35]@40320
// total 40355 floats (~158 KB) — well under any plausible ws_size.

#define NN 35
#define NE 1190
#define TE2 7   // edges per block in msg kernels; 1190 = 170*7 exactly

__global__ void zero_k(float* p, int n) {
    int t = blockIdx.x * 256 + threadIdx.x;
    if (t < n) p[t] = 0.f;
}

// Layer 1: c_in=1, c_out=256. msg[e,o] = x[src]*relu(ea·w1[o]+b1w[o]); scatter.
__global__ __launch_bounds__(256) void msg1_k(
    const float* __restrict__ x, const float* __restrict__ ea,
    const int* __restrict__ ei, const float* __restrict__ w1,
    const float* __restrict__ b1w, float* __restrict__ agg1,
    float* __restrict__ cnt) {
    int e = blockIdx.x;
    int o = threadIdx.x;
    int src = ei[e];
    int dst = ei[NE + e];
    float xs = x[src];
    const float* eap = ea + e * 6;
    const float* w = w1 + o * 6;
    float d = b1w[o];
#pragma unroll
    for (int v = 0; v < 6; v++) d = fmaf(eap[v], w[v], d);
    atomicAdd(agg1 + dst * 256 + o, xs * fmaxf(d, 0.f));
    if (o == 0) atomicAdd(cnt + dst, 1.0f);
}

__global__ __launch_bounds__(256) void x1_k(
    const float* __restrict__ x, const float* __restrict__ lin1,
    const float* __restrict__ b1, const float* __restrict__ agg1,
    const float* __restrict__ cnt, float* __restrict__ x1) {
    int n = blockIdx.x, o = threadIdx.x;
    float c = fmaxf(cnt[n], 1.f);
    float v = agg1[n * 256 + o] / c + x[n] * lin1[o] + b1[o];
    x1[n * 256 + o] = fmaxf(v, 0.f);
}

// Layer 2: c_in=256, c_out=256. Block: TE2 edges x 256 o-threads, i-loop.
__global__ __launch_bounds__(256) void msg2_k(
    const float* __restrict__ x1, const float* __restrict__ ea,
    const int* __restrict__ ei, const float* __restrict__ w2,
    const float* __restrict__ b2w, float* __restrict__ agg2) {
    __shared__ float xs[TE2][256];
    __shared__ float eas[TE2][6];
    __shared__ int dsts[TE2];
    int tid = threadIdx.x;
    int e0 = blockIdx.x * TE2;
    if (tid < TE2) dsts[tid] = ei[NE + e0 + tid];
    if (tid < TE2 * 6) {
        int te = tid / 6, v = tid % 6;
        eas[te][v] = ea[(e0 + te) * 6 + v];
    }
    for (int idx = tid; idx < TE2 * 256; idx += 256) {
        int te = idx >> 8, i = idx & 255;
        int s = ei[e0 + te];
        xs[te][i] = x1[s * 256 + i];
    }
    __syncthreads();
    float eareg[TE2][6];
#pragma unroll
    for (int te = 0; te < TE2; te++)
#pragma unroll
        for (int v = 0; v < 6; v++) eareg[te][v] = eas[te][v];
    float acc[TE2] = {};
    int o = tid;
    for (int i = 0; i < 256; i++) {
        const float* w = w2 + (size_t)(i * 256 + o) * 6;
        float2 wa = *(const float2*)w;
        float2 wb = *(const float2*)(w + 2);
        float2 wc = *(const float2*)(w + 4);
        float b = b2w[i * 256 + o];
#pragma unroll
        for (int te = 0; te < TE2; te++) {
            float d = b;
            d = fmaf(eareg[te][0], wa.x, d);
            d = fmaf(eareg[te][1], wa.y, d);
            d = fmaf(eareg[te][2], wb.x, d);
            d = fmaf(eareg[te][3], wb.y, d);
            d = fmaf(eareg[te][4], wc.x, d);
            d = fmaf(eareg[te][5], wc.y, d);
            acc[te] = fmaf(xs[te][i], fmaxf(d, 0.f), acc[te]);
        }
    }
#pragma unroll
    for (int te = 0; te < TE2; te++)
        atomicAdd(agg2 + dsts[te] * 256 + o, acc[te]);
}

__global__ __launch_bounds__(256) void x2_k(
    const float* __restrict__ x1, const float* __restrict__ lin2,
    const float* __restrict__ b2, const float* __restrict__ agg2,
    const float* __restrict__ cnt, float* __restrict__ x2) {
    __shared__ float xr[256];
    int n = blockIdx.x, o = threadIdx.x;
    xr[o] = x1[n * 256 + o];
    __syncthreads();
    float c = fmaxf(cnt[n], 1.f);
    const float* w = lin2 + o * 256;
    float s = 0.f;
    for (int i = 0; i < 256; i++) s = fmaf(xr[i], w[i], s);
    float v = agg2[n * 256 + o] / c + s + b2[o];
    x2[n * 256 + o] = fmaxf(v, 0.f);
}

// Layer 3: c_in=256, c_out=64. 256 threads = 4 i-chunks x 64 o.
__global__ __launch_bounds__(256) void msg3_k(
    const float* __restrict__ x2, const float* __restrict__ ea,
    const int* __restrict__ ei, const float* __restrict__ w3,
    const float* __restrict__ b3w, float* __restrict__ agg3) {
    __shared__ float xs[TE2][256];
    __shared__ float eas[TE2][6];
    __shared__ int dsts[TE2];
    __shared__ float part[3][TE2][64];
    int tid = threadIdx.x;
    int e0 = blockIdx.x * TE2;
    if (tid < TE2) dsts[tid] = ei[NE + e0 + tid];
    if (tid < TE2 * 6) {
        int te = tid / 6, v = tid % 6;
        eas[te][v] = ea[(e0 + te) * 6 + v];
    }
    for (int idx = tid; idx < TE2 * 256; idx += 256) {
        int te = idx >> 8, i = idx & 255;
        int s = ei[e0 + te];
        xs[te][i] = x2[s * 256 + i];
    }
    __syncthreads();
    float eareg[TE2][6];
#pragma unroll
    for (int te = 0; te < TE2; te++)
#pragma unroll
        for (int v = 0; v < 6; v++) eareg[te][v] = eas[te][v];
    int o = tid & 63;
    int ic = tid >> 6;  // 0..3, i range [ic*64, ic*64+64)
    float acc[TE2] = {};
    for (int ii = 0; ii < 64; ii++) {
        int i = ic * 64 + ii;
        const float* w = w3 + (size_t)(i * 64 + o) * 6;
        float2 wa = *(const float2*)w;
        float2 wb = *(const float2*)(w + 2);
        float2 wc = *(const float2*)(w + 4);
        float b = b3w[i * 64 + o];
#pragma unroll
        for (int te = 0; te < TE2; te++) {
            float d = b;
            d = fmaf(eareg[te][0], wa.x, d);
            d = fmaf(eareg[te][1], wa.y, d);
            d = fmaf(eareg[te][2], wb.x, d);
            d = fmaf(eareg[te][3], wb.y, d);
            d = fmaf(eareg[te][4], wc.x, d);
            d = fmaf(eareg[te][5], wc.y, d);
            acc[te] = fmaf(xs[te][i], fmaxf(d, 0.f), acc[te]);
        }
    }
    if (ic > 0) {
#pragma unroll
        for (int te = 0; te < TE2; te++) part[ic - 1][te][o] = acc[te];
    }
    __syncthreads();
    if (ic == 0) {
#pragma unroll
        for (int te = 0; te < TE2; te++) {
            float s = acc[te] + part[0][te][o] + part[1][te][o] + part[2][te][o];
            atomicAdd(agg3 + dsts[te] * 64 + o, s);
        }
    }
}

__global__ __launch_bounds__(64) void x3_k(
    const float* __restrict__ x2, const float* __restrict__ lin3,
    const float* __restrict__ b3, const float* __restrict__ agg3,
    const float* __restrict__ cnt, float* __restrict__ x3) {
    __shared__ float xr[256];
    int n = blockIdx.x, o = threadIdx.x;  // 64 threads
    for (int idx = o; idx < 256; idx += 64) xr[idx] = x2[n * 256 + idx];
    __syncthreads();
    float c = fmaxf(cnt[n], 1.f);
    const float* w = lin3 + o * 256;
    float s = 0.f;
    for (int i = 0; i < 256; i++) s = fmaf(xr[i], w[i], s);
    x3[n * 64 + o] = fmaxf(agg3[n * 64 + o] / c + s + b3[o], 0.f);
}

__global__ __launch_bounds__(256) void cbt_k(const float* __restrict__ x3,
                                             float* __restrict__ out) {
    int t = blockIdx.x * 256 + threadIdx.x;
    if (t >= NN * NN) return;
    int i = t / NN, j = t % NN;
    const float* a = x3 + i * 64;
    const float* b = x3 + j * 64;
    float s = 0.f;
#pragma unroll
    for (int f = 0; f < 64; f++) s += fabsf(a[f] - b[f]);
    out[t] = s;
}

extern "C" void kernel_launch(void* const* d_in, const int* in_sizes, int n_in,
                              void* d_out, int out_size, void* d_ws, size_t ws_size,
                              hipStream_t stream) {
    const float* x    = (const float*)d_in[0];
    const float* ea   = (const float*)d_in[1];
    const int*   ei   = (const int*)d_in[2];
    const float* nn1w = (const float*)d_in[3];
    const float* nn1b = (const float*)d_in[4];
    const float* lin1 = (const float*)d_in[5];
    const float* b1   = (const float*)d_in[6];
    const float* nn2w = (const float*)d_in[7];
    const float* nn2b = (const float*)d_in[8];
    const float* lin2 = (const float*)d_in[9];
    const float* b2   = (const float*)d_in[10];
    const float* nn3w = (const float*)d_in[11];
    const float* nn3b = (const float*)d_in[12];
    const float* lin3 = (const float*)d_in[13];
    const float* b3   = (const float*)d_in[14];

    float* ws   = (float*)d_ws;
    float* x1   = ws;
    float* x2   = ws + 8960;
    float* x3v  = ws + 17920;
    float* agg1 = ws + 20160;
    float* agg2 = ws + 29120;
    float* agg3 = ws + 38080;
    float* cnt  = ws + 40320;
    float* out  = (float*)d_out;

    // zero agg1..cnt (contiguous 20195 floats starting at agg1)
    zero_k<<<(20195 + 255) / 256, 256, 0, stream>>>(agg1, 20195);
    msg1_k<<<NE, 256, 0, stream>>>(x, ea, ei, nn1w, nn1b, agg1, cnt);
    x1_k<<<NN, 256, 0, stream>>>(x, lin1, b1, agg1, cnt, x1);
    msg2_k<<<NE / TE2, 256, 0, stream>>>(x1, ea, ei, nn2w, nn2b, agg2);
    x2_k<<<NN, 256, 0, stream>>>(x1, lin2, b2, agg2, cnt, x2);
    msg3_k<<<NE / TE2, 256, 0, stream>>>(x2, ea, ei, nn3w, nn3b, agg3);
    x3_k<<<NN, 64, 0, stream>>>(x2, lin3, b3, agg3, cnt, x3v);
    cbt_k<<<(NN * NN + 255) / 256, 256, 0, stream>>>(x3v, out);
}

// Round 2
// 159.787 us; speedup vs baseline: 1.6161x; 1.6161x over previous
//
#include <hip/hip_runtime.h>

// MGN_NET: 3x NNConv(mean) + ReLU, then pairwise-L1 CBT [35x35].
// All fp32. ws layout (floats):
//   x1[35*256]@0, x2[35*256]@8960, x3[35*64]@17920,
//   agg1[8960]@20160, agg2[8960]@29120, agg3[2240]@38080, cnt[35]@40320

#define NN 35
#define NE 1190
#define TE 5   // edges per block in msg2/msg3; 1190 = 238*5 exactly

__global__ void zero_k(float* p, int n) {
    int t = blockIdx.x * 256 + threadIdx.x;
    if (t < n) p[t] = 0.f;
}

// Layer 1: c_in=1, c_out=256. msg[e,o] = x[src]*relu(ea·w1[o]+b1w[o]); scatter.
__global__ __launch_bounds__(256) void msg1_k(
    const float* __restrict__ x, const float* __restrict__ ea,
    const int* __restrict__ ei, const float* __restrict__ w1,
    const float* __restrict__ b1w, float* __restrict__ agg1,
    float* __restrict__ cnt) {
    int e = blockIdx.x;
    int o = threadIdx.x;
    int src = ei[e];
    int dst = ei[NE + e];
    float xs = x[src];
    const float* eap = ea + e * 6;
    const float* w = w1 + o * 6;
    float d = b1w[o];
#pragma unroll
    for (int v = 0; v < 6; v++) d = fmaf(eap[v], w[v], d);
    atomicAdd(agg1 + dst * 256 + o, xs * fmaxf(d, 0.f));
    if (o == 0) atomicAdd(cnt + dst, 1.0f);
}

__global__ __launch_bounds__(256) void x1_k(
    const float* __restrict__ x, const float* __restrict__ lin1,
    const float* __restrict__ b1, const float* __restrict__ agg1,
    const float* __restrict__ cnt, float* __restrict__ x1) {
    int n = blockIdx.x, o = threadIdx.x;
    float c = fmaxf(cnt[n], 1.f);
    float v = agg1[n * 256 + o] / c + x[n] * lin1[o] + b1[o];
    x1[n * 256 + o] = fmaxf(v, 0.f);
}

// Layer 2: c_in=256, c_out=256. Block: 1024 thr = 256 o x 4 i-chunks, TE edges.
__global__ __launch_bounds__(1024) void msg2_k(
    const float* __restrict__ x1, const float* __restrict__ ea,
    const int* __restrict__ ei, const float* __restrict__ w2,
    const float* __restrict__ b2w, float* __restrict__ agg2) {
    __shared__ float xs[TE][256];
    __shared__ float eas[TE][6];
    __shared__ int dsts[TE];
    __shared__ int srcs[TE];
    __shared__ float part[3][TE][256];
    int tid = threadIdx.x;
    int e0 = blockIdx.x * TE;
    if (tid < TE) { dsts[tid] = ei[NE + e0 + tid]; srcs[tid] = ei[e0 + tid]; }
    if (tid >= 64 && tid < 64 + TE * 6) {
        int t = tid - 64;
        eas[t / 6][t % 6] = ea[e0 * 6 + t];
    }
    __syncthreads();
    for (int idx = tid; idx < TE * 256; idx += 1024) {
        int te = idx >> 8, i = idx & 255;
        xs[te][i] = x1[srcs[te] * 256 + i];
    }
    __syncthreads();
    int o = tid & 255;
    int ic = tid >> 8;  // 0..3, i in [ic*64, ic*64+64)
    float eareg[TE][6];
#pragma unroll
    for (int te = 0; te < TE; te++)
#pragma unroll
        for (int v = 0; v < 6; v++) eareg[te][v] = eas[te][v];
    float acc[TE] = {};
    for (int ii = 0; ii < 64; ii++) {
        int i = ic * 64 + ii;
        const float* w = w2 + (size_t)(i * 256 + o) * 6;
        float2 wa = *(const float2*)w;
        float2 wb = *(const float2*)(w + 2);
        float2 wc = *(const float2*)(w + 4);
        float b = b2w[i * 256 + o];
        float xv = xs[0][i];  // dummy init pattern; real loads below
#pragma unroll
        for (int te = 0; te < TE; te++) {
            float d = b;
            d = fmaf(eareg[te][0], wa.x, d);
            d = fmaf(eareg[te][1], wa.y, d);
            d = fmaf(eareg[te][2], wb.x, d);
            d = fmaf(eareg[te][3], wb.y, d);
            d = fmaf(eareg[te][4], wc.x, d);
            d = fmaf(eareg[te][5], wc.y, d);
            acc[te] = fmaf(xs[te][i], fmaxf(d, 0.f), acc[te]);
        }
        (void)xv;
    }
    if (ic > 0) {
#pragma unroll
        for (int te = 0; te < TE; te++) part[ic - 1][te][o] = acc[te];
    }
    __syncthreads();
    if (ic == 0) {
#pragma unroll
        for (int te = 0; te < TE; te++) {
            float s = acc[te] + part[0][te][o] + part[1][te][o] + part[2][te][o];
            atomicAdd(agg2 + dsts[te] * 256 + o, s);
        }
    }
}

__global__ __launch_bounds__(1024) void x2_k(
    const float* __restrict__ x1, const float* __restrict__ lin2,
    const float* __restrict__ b2, const float* __restrict__ agg2,
    const float* __restrict__ cnt, float* __restrict__ x2) {
    __shared__ float xr[256];
    __shared__ float part[3][256];
    int n = blockIdx.x, tid = threadIdx.x;
    int o = tid & 255, ic = tid >> 8;
    if (tid < 256) xr[tid] = x1[n * 256 + tid];
    __syncthreads();
    const float4* w = (const float4*)(lin2 + (size_t)o * 256 + ic * 64);
    float s = 0.f;
#pragma unroll
    for (int k = 0; k < 16; k++) {
        float4 wv = w[k];
        int i = ic * 64 + k * 4;
        s = fmaf(wv.x, xr[i], s);
        s = fmaf(wv.y, xr[i + 1], s);
        s = fmaf(wv.z, xr[i + 2], s);
        s = fmaf(wv.w, xr[i + 3], s);
    }
    if (ic > 0) part[ic - 1][o] = s;
    __syncthreads();
    if (ic == 0) {
        float tot = s + part[0][o] + part[1][o] + part[2][o];
        float c = fmaxf(cnt[n], 1.f);
        float v = agg2[n * 256 + o] / c + tot + b2[o];
        x2[n * 256 + o] = fmaxf(v, 0.f);
    }
}

// Layer 3: c_in=256, c_out=64. Block: 512 thr = 64 o x 8 i-chunks, TE edges.
__global__ __launch_bounds__(512) void msg3_k(
    const float* __restrict__ x2, const float* __restrict__ ea,
    const int* __restrict__ ei, const float* __restrict__ w3,
    const float* __restrict__ b3w, float* __restrict__ agg3) {
    __shared__ float xs[TE][256];
    __shared__ float eas[TE][6];
    __shared__ int dsts[TE];
    __shared__ int srcs[TE];
    __shared__ float part[7][TE][64];
    int tid = threadIdx.x;
    int e0 = blockIdx.x * TE;
    if (tid < TE) { dsts[tid] = ei[NE + e0 + tid]; srcs[tid] = ei[e0 + tid]; }
    if (tid >= 64 && tid < 64 + TE * 6) {
        int t = tid - 64;
        eas[t / 6][t % 6] = ea[e0 * 6 + t];
    }
    __syncthreads();
    for (int idx = tid; idx < TE * 256; idx += 512) {
        int te = idx >> 8, i = idx & 255;
        xs[te][i] = x2[srcs[te] * 256 + i];
    }
    __syncthreads();
    int o = tid & 63;
    int ic = tid >> 6;  // 0..7, i in [ic*32, ic*32+32)
    float eareg[TE][6];
#pragma unroll
    for (int te = 0; te < TE; te++)
#pragma unroll
        for (int v = 0; v < 6; v++) eareg[te][v] = eas[te][v];
    float acc[TE] = {};
    for (int ii = 0; ii < 32; ii++) {
        int i = ic * 32 + ii;
        const float* w = w3 + (size_t)(i * 64 + o) * 6;
        float2 wa = *(const float2*)w;
        float2 wb = *(const float2*)(w + 2);
        float2 wc = *(const float2*)(w + 4);
        float b = b3w[i * 64 + o];
#pragma unroll
        for (int te = 0; te < TE; te++) {
            float d = b;
            d = fmaf(eareg[te][0], wa.x, d);
            d = fmaf(eareg[te][1], wa.y, d);
            d = fmaf(eareg[te][2], wb.x, d);
            d = fmaf(eareg[te][3], wb.y, d);
            d = fmaf(eareg[te][4], wc.x, d);
            d = fmaf(eareg[te][5], wc.y, d);
            acc[te] = fmaf(xs[te][i], fmaxf(d, 0.f), acc[te]);
        }
    }
    if (ic > 0) {
#pragma unroll
        for (int te = 0; te < TE; te++) part[ic - 1][te][o] = acc[te];
    }
    __syncthreads();
    if (ic == 0) {
#pragma unroll
        for (int te = 0; te < TE; te++) {
            float s = acc[te];
#pragma unroll
            for (int p = 0; p < 7; p++) s += part[p][te][o];
            atomicAdd(agg3 + dsts[te] * 64 + o, s);
        }
    }
}

__global__ __launch_bounds__(256) void x3_k(
    const float* __restrict__ x2, const float* __restrict__ lin3,
    const float* __restrict__ b3, const float* __restrict__ agg3,
    const float* __restrict__ cnt, float* __restrict__ x3) {
    __shared__ float xr[256];
    __shared__ float part[3][64];
    int n = blockIdx.x, tid = threadIdx.x;
    int o = tid & 63, ic = tid >> 6;  // 4 chunks of 64
    if (tid < 256) {
        if (tid < 256) xr[tid] = x2[n * 256 + tid];
    }
    __syncthreads();
    const float4* w = (const float4*)(lin3 + (size_t)o * 256 + ic * 64);
    float s = 0.f;
#pragma unroll
    for (int k = 0; k < 16; k++) {
        float4 wv = w[k];
        int i = ic * 64 + k * 4;
        s = fmaf(wv.x, xr[i], s);
        s = fmaf(wv.y, xr[i + 1], s);
        s = fmaf(wv.z, xr[i + 2], s);
        s = fmaf(wv.w, xr[i + 3], s);
    }
    if (ic > 0) part[ic - 1][o] = s;
    __syncthreads();
    if (ic == 0) {
        float tot = s + part[0][o] + part[1][o] + part[2][o];
        float c = fmaxf(cnt[n], 1.f);
        x3[n * 64 + o] = fmaxf(agg3[n * 64 + o] / c + tot + b3[o], 0.f);
    }
}

__global__ __launch_bounds__(256) void cbt_k(const float* __restrict__ x3,
                                             float* __restrict__ out) {
    int t = blockIdx.x * 256 + threadIdx.x;
    if (t >= NN * NN) return;
    int i = t / NN, j = t % NN;
    const float* a = x3 + i * 64;
    const float* b = x3 + j * 64;
    float s = 0.f;
#pragma unroll
    for (int f = 0; f < 64; f++) s += fabsf(a[f] - b[f]);
    out[t] = s;
}

extern "C" void kernel_launch(void* const* d_in, const int* in_sizes, int n_in,
                              void* d_out, int out_size, void* d_ws, size_t ws_size,
                              hipStream_t stream) {
    const float* x    = (const float*)d_in[0];
    const float* ea   = (const float*)d_in[1];
    const int*   ei   = (const int*)d_in[2];
    const float* nn1w = (const float*)d_in[3];
    const float* nn1b = (const float*)d_in[4];
    const float* lin1 = (const float*)d_in[5];
    const float* b1   = (const float*)d_in[6];
    const float* nn2w = (const float*)d_in[7];
    const float* nn2b = (const float*)d_in[8];
    const float* lin2 = (const float*)d_in[9];
    const float* b2   = (const float*)d_in[10];
    const float* nn3w = (const float*)d_in[11];
    const float* nn3b = (const float*)d_in[12];
    const float* lin3 = (const float*)d_in[13];
    const float* b3   = (const float*)d_in[14];

    float* ws   = (float*)d_ws;
    float* x1   = ws;
    float* x2   = ws + 8960;
    float* x3v  = ws + 17920;
    float* agg1 = ws + 20160;
    float* agg2 = ws + 29120;
    float* agg3 = ws + 38080;
    float* cnt  = ws + 40320;
    float* out  = (float*)d_out;

    // zero agg1..cnt (contiguous 20195 floats starting at agg1)
    zero_k<<<(20195 + 255) / 256, 256, 0, stream>>>(agg1, 20195);
    msg1_k<<<NE, 256, 0, stream>>>(x, ea, ei, nn1w, nn1b, agg1, cnt);
    x1_k<<<NN, 256, 0, stream>>>(x, lin1, b1, agg1, cnt, x1);
    msg2_k<<<NE / TE, 1024, 0, stream>>>(x1, ea, ei, nn2w, nn2b, agg2);
    x2_k<<<NN, 1024, 0, stream>>>(x1, lin2, b2, agg2, cnt, x2);
    msg3_k<<<NE / TE, 512, 0, stream>>>(x2, ea, ei, nn3w, nn3b, agg3);
    x3_k<<<NN, 256, 0, stream>>>(x2, lin3, b3, agg3, cnt, x3v);
    cbt_k<<<(NN * NN + 255) / 256, 256, 0, stream>>>(x3v, out);
}

// Round 3
// 146.971 us; speedup vs baseline: 1.7570x; 1.0872x over previous
//
#include <hip/hip_runtime.h>

// MGN_NET: 3x NNConv(mean) + ReLU, then pairwise-L1 CBT [35x35].
// All fp32. ws layout (floats):
//   x1[35*256]@0, x2[35*256]@8960, x3[35*64]@17920,
//   agg1[8960]@20160, agg2[8960]@29120, agg3[2240]@38080, cnt[35]@40320

#define NN 35
#define NE 1190
#define TE 5   // edges per edge-group; 1190 = 238*5 exactly

__global__ void zero_k(float* p, int n) {
    int t = blockIdx.x * 256 + threadIdx.x;
    if (t < n) p[t] = 0.f;
}

// Layer 1: c_in=1, c_out=256. msg[e,o] = x[src]*relu(ea·w1[o]+b1w[o]); scatter.
__global__ __launch_bounds__(256) void msg1_k(
    const float* __restrict__ x, const float* __restrict__ ea,
    const int* __restrict__ ei, const float* __restrict__ w1,
    const float* __restrict__ b1w, float* __restrict__ agg1,
    float* __restrict__ cnt) {
    int e = blockIdx.x;
    int o = threadIdx.x;
    int src = ei[e];
    int dst = ei[NE + e];
    float xs = x[src];
    const float* eap = ea + e * 6;
    const float* w = w1 + o * 6;
    float d = b1w[o];
#pragma unroll
    for (int v = 0; v < 6; v++) d = fmaf(eap[v], w[v], d);
    atomicAdd(agg1 + dst * 256 + o, xs * fmaxf(d, 0.f));
    if (o == 0) atomicAdd(cnt + dst, 1.0f);
}

__global__ __launch_bounds__(256) void x1_k(
    const float* __restrict__ x, const float* __restrict__ lin1,
    const float* __restrict__ b1, const float* __restrict__ agg1,
    const float* __restrict__ cnt, float* __restrict__ x1) {
    int n = blockIdx.x, o = threadIdx.x;
    float c = fmaxf(cnt[n], 1.f);
    float v = agg1[n * 256 + o] / c + x[n] * lin1[o] + b1[o];
    x1[n * 256 + o] = fmaxf(v, 0.f);
}

// Layer 2: c_in=256, c_out=256.
// Grid = 238 edge-groups x 4 o-groups; block 512 = 64 o-lanes x 8 i-chunks.
// Each block reads w2 slice [256 i][64 o] once (0.46 MB); total 436 MB from L2.
__global__ __launch_bounds__(512) void msg2_k(
    const float* __restrict__ x1, const float* __restrict__ ea,
    const int* __restrict__ ei, const float* __restrict__ w2,
    const float* __restrict__ b2w, float* __restrict__ agg2) {
    __shared__ float xs[TE][256];
    __shared__ float eas[TE][6];
    __shared__ int dsts[TE];
    __shared__ int srcs[TE];
    __shared__ float part[7][TE][64];
    int tid = threadIdx.x;
    int eg = blockIdx.x >> 2;
    int og = blockIdx.x & 3;
    int e0 = eg * TE;
    if (tid < TE) { dsts[tid] = ei[NE + e0 + tid]; srcs[tid] = ei[e0 + tid]; }
    if (tid >= 64 && tid < 64 + TE * 6) {
        int t = tid - 64;
        eas[t / 6][t % 6] = ea[e0 * 6 + t];
    }
    __syncthreads();
    for (int idx = tid; idx < TE * 256; idx += 512) {
        int te = idx >> 8, i = idx & 255;
        xs[te][i] = x1[srcs[te] * 256 + i];
    }
    __syncthreads();
    int ol = tid & 63;
    int o = og * 64 + ol;
    int ic = tid >> 6;  // 0..7, i in [ic*32, ic*32+32)
    float eareg[TE][6];
#pragma unroll
    for (int te = 0; te < TE; te++)
#pragma unroll
        for (int v = 0; v < 6; v++) eareg[te][v] = eas[te][v];
    float acc[TE] = {};
    for (int ii = 0; ii < 32; ii++) {
        int i = ic * 32 + ii;
        const float* w = w2 + (size_t)(i * 256 + o) * 6;
        float2 wa = *(const float2*)w;
        float2 wb = *(const float2*)(w + 2);
        float2 wc = *(const float2*)(w + 4);
        float b = b2w[i * 256 + o];
#pragma unroll
        for (int te = 0; te < TE; te++) {
            float d = b;
            d = fmaf(eareg[te][0], wa.x, d);
            d = fmaf(eareg[te][1], wa.y, d);
            d = fmaf(eareg[te][2], wb.x, d);
            d = fmaf(eareg[te][3], wb.y, d);
            d = fmaf(eareg[te][4], wc.x, d);
            d = fmaf(eareg[te][5], wc.y, d);
            acc[te] = fmaf(xs[te][i], fmaxf(d, 0.f), acc[te]);
        }
    }
    if (ic > 0) {
#pragma unroll
        for (int te = 0; te < TE; te++) part[ic - 1][te][ol] = acc[te];
    }
    __syncthreads();
    if (ic == 0) {
#pragma unroll
        for (int te = 0; te < TE; te++) {
            float s = acc[te];
#pragma unroll
            for (int p = 0; p < 7; p++) s += part[p][te][ol];
            atomicAdd(agg2 + dsts[te] * 256 + o, s);
        }
    }
}

__global__ __launch_bounds__(1024) void x2_k(
    const float* __restrict__ x1, const float* __restrict__ lin2,
    const float* __restrict__ b2, const float* __restrict__ agg2,
    const float* __restrict__ cnt, float* __restrict__ x2) {
    __shared__ float xr[256];
    __shared__ float part[3][256];
    int n = blockIdx.x, tid = threadIdx.x;
    int o = tid & 255, ic = tid >> 8;
    if (tid < 256) xr[tid] = x1[n * 256 + tid];
    __syncthreads();
    const float4* w = (const float4*)(lin2 + (size_t)o * 256 + ic * 64);
    float s = 0.f;
#pragma unroll
    for (int k = 0; k < 16; k++) {
        float4 wv = w[k];
        int i = ic * 64 + k * 4;
        s = fmaf(wv.x, xr[i], s);
        s = fmaf(wv.y, xr[i + 1], s);
        s = fmaf(wv.z, xr[i + 2], s);
        s = fmaf(wv.w, xr[i + 3], s);
    }
    if (ic > 0) part[ic - 1][o] = s;
    __syncthreads();
    if (ic == 0) {
        float tot = s + part[0][o] + part[1][o] + part[2][o];
        float c = fmaxf(cnt[n], 1.f);
        float v = agg2[n * 256 + o] / c + tot + b2[o];
        x2[n * 256 + o] = fmaxf(v, 0.f);
    }
}

// Layer 3: c_in=256, c_out=64.
// Grid = 238 edge-groups x 2 i-groups; block 512 = 64 o x 8 i-chunks of 16.
// Each i-group covers i in [ig*128, ig*128+128); partial sums go through the
// same agg3 atomics (adds are associative-enough for the 0.45 threshold).
__global__ __launch_bounds__(512) void msg3_k(
    const float* __restrict__ x2, const float* __restrict__ ea,
    const int* __restrict__ ei, const float* __restrict__ w3,
    const float* __restrict__ b3w, float* __restrict__ agg3) {
    __shared__ float xs[TE][128];
    __shared__ float eas[TE][6];
    __shared__ int dsts[TE];
    __shared__ int srcs[TE];
    __shared__ float part[7][TE][64];
    int tid = threadIdx.x;
    int eg = blockIdx.x >> 1;
    int ig = blockIdx.x & 1;
    int e0 = eg * TE;
    if (tid < TE) { dsts[tid] = ei[NE + e0 + tid]; srcs[tid] = ei[e0 + tid]; }
    if (tid >= 64 && tid < 64 + TE * 6) {
        int t = tid - 64;
        eas[t / 6][t % 6] = ea[e0 * 6 + t];
    }
    __syncthreads();
    for (int idx = tid; idx < TE * 128; idx += 512) {
        int te = idx >> 7, ii = idx & 127;
        xs[te][ii] = x2[srcs[te] * 256 + ig * 128 + ii];
    }
    __syncthreads();
    int ol = tid & 63;
    int ic = tid >> 6;  // 0..7, 16 i each
    float eareg[TE][6];
#pragma unroll
    for (int te = 0; te < TE; te++)
#pragma unroll
        for (int v = 0; v < 6; v++) eareg[te][v] = eas[te][v];
    float acc[TE] = {};
    for (int jj = 0; jj < 16; jj++) {
        int ii = ic * 16 + jj;           // local i within this i-group
        int i = ig * 128 + ii;           // global i
        const float* w = w3 + (size_t)(i * 64 + ol) * 6;
        float2 wa = *(const float2*)w;
        float2 wb = *(const float2*)(w + 2);
        float2 wc = *(const float2*)(w + 4);
        float b = b3w[i * 64 + ol];
#pragma unroll
        for (int te = 0; te < TE; te++) {
            float d = b;
            d = fmaf(eareg[te][0], wa.x, d);
            d = fmaf(eareg[te][1], wa.y, d);
            d = fmaf(eareg[te][2], wb.x, d);
            d = fmaf(eareg[te][3], wb.y, d);
            d = fmaf(eareg[te][4], wc.x, d);
            d = fmaf(eareg[te][5], wc.y, d);
            acc[te] = fmaf(xs[te][ii], fmaxf(d, 0.f), acc[te]);
        }
    }
    if (ic > 0) {
#pragma unroll
        for (int te = 0; te < TE; te++) part[ic - 1][te][ol] = acc[te];
    }
    __syncthreads();
    if (ic == 0) {
#pragma unroll
        for (int te = 0; te < TE; te++) {
            float s = acc[te];
#pragma unroll
            for (int p = 0; p < 7; p++) s += part[p][te][ol];
            atomicAdd(agg3 + dsts[te] * 64 + ol, s);
        }
    }
}

__global__ __launch_bounds__(256) void x3_k(
    const float* __restrict__ x2, const float* __restrict__ lin3,
    const float* __restrict__ b3, const float* __restrict__ agg3,
    const float* __restrict__ cnt, float* __restrict__ x3) {
    __shared__ float xr[256];
    __shared__ float part[3][64];
    int n = blockIdx.x, tid = threadIdx.x;
    int o = tid & 63, ic = tid >> 6;  // 4 chunks of 64
    xr[tid] = x2[n * 256 + tid];
    __syncthreads();
    const float4* w = (const float4*)(lin3 + (size_t)o * 256 + ic * 64);
    float s = 0.f;
#pragma unroll
    for (int k = 0; k < 16; k++) {
        float4 wv = w[k];
        int i = ic * 64 + k * 4;
        s = fmaf(wv.x, xr[i], s);
        s = fmaf(wv.y, xr[i + 1], s);
        s = fmaf(wv.z, xr[i + 2], s);
        s = fmaf(wv.w, xr[i + 3], s);
    }
    if (ic > 0) part[ic - 1][o] = s;
    __syncthreads();
    if (ic == 0) {
        float tot = s + part[0][o] + part[1][o] + part[2][o];
        float c = fmaxf(cnt[n], 1.f);
        x3[n * 64 + o] = fmaxf(agg3[n * 64 + o] / c + tot + b3[o], 0.f);
    }
}

__global__ __launch_bounds__(256) void cbt_k(const float* __restrict__ x3,
                                             float* __restrict__ out) {
    int t = blockIdx.x * 256 + threadIdx.x;
    if (t >= NN * NN) return;
    int i = t / NN, j = t % NN;
    const float* a = x3 + i * 64;
    const float* b = x3 + j * 64;
    float s = 0.f;
#pragma unroll
    for (int f = 0; f < 64; f++) s += fabsf(a[f] - b[f]);
    out[t] = s;
}

extern "C" void kernel_launch(void* const* d_in, const int* in_sizes, int n_in,
                              void* d_out, int out_size, void* d_ws, size_t ws_size,
                              hipStream_t stream) {
    const float* x    = (const float*)d_in[0];
    const float* ea   = (const float*)d_in[1];
    const int*   ei   = (const int*)d_in[2];
    const float* nn1w = (const float*)d_in[3];
    const float* nn1b = (const float*)d_in[4];
    const float* lin1 = (const float*)d_in[5];
    const float* b1   = (const float*)d_in[6];
    const float* nn2w = (const float*)d_in[7];
    const float* nn2b = (const float*)d_in[8];
    const float* lin2 = (const float*)d_in[9];
    const float* b2   = (const float*)d_in[10];
    const float* nn3w = (const float*)d_in[11];
    const float* nn3b = (const float*)d_in[12];
    const float* lin3 = (const float*)d_in[13];
    const float* b3   = (const float*)d_in[14];

    float* ws   = (float*)d_ws;
    float* x1   = ws;
    float* x2   = ws + 8960;
    float* x3v  = ws + 17920;
    float* agg1 = ws + 20160;
    float* agg2 = ws + 29120;
    float* agg3 = ws + 38080;
    float* cnt  = ws + 40320;
    float* out  = (float*)d_out;

    // zero agg1..cnt (contiguous 20195 floats starting at agg1)
    zero_k<<<(20195 + 255) / 256, 256, 0, stream>>>(agg1, 20195);
    msg1_k<<<NE, 256, 0, stream>>>(x, ea, ei, nn1w, nn1b, agg1, cnt);
    x1_k<<<NN, 256, 0, stream>>>(x, lin1, b1, agg1, cnt, x1);
    msg2_k<<<238 * 4, 512, 0, stream>>>(x1, ea, ei, nn2w, nn2b, agg2);
    x2_k<<<NN, 1024, 0, stream>>>(x1, lin2, b2, agg2, cnt, x2);
    msg3_k<<<238 * 2, 512, 0, stream>>>(x2, ea, ei, nn3w, nn3b, agg3);
    x3_k<<<NN, 256, 0, stream>>>(x2, lin3, b3, agg3, cnt, x3v);
    cbt_k<<<(NN * NN + 255) / 256, 256, 0, stream>>>(x3v, out);
}